// Round 13
// baseline (333.147 us; speedup 1.0000x reference)
//
#include <hip/hip_runtime.h>
#include <hip/hip_fp16.h>
#include <stdint.h>

#define NNODES 50000
#define NEDGES 800000
#define NHID 96
#define NCLS 16
#define NB ((NNODES + 255) / 256)   // 196 scan blocks

// graph build: NC edge-chunks x NR node-ranges; per-block LDS histogram of one
// range (12500 nodes, u16 pair-packed into 6250 u32 words). grid = NC*NR = 800.
#define NC 200
#define NR 4
#define EPB (NEDGES / NC)           // 4000 edges per chunk
#define RNODES (NNODES / NR)        // 12500 nodes per range
#define RWORDS (RNODES / 2)         // 6250 packed words
#define NWORDS (NNODES / 2)         // 25000 global packed words

// ---------- JAX Threefry-2x32 (Random123 20-round, matches jax._src.prng) ----------
__host__ __device__ inline void tf2x32(uint32_t k0, uint32_t k1, uint32_t x0, uint32_t x1,
                                       uint32_t& o0, uint32_t& o1) {
  uint32_t k2 = k0 ^ k1 ^ 0x1BD11BDAu;
#define TFROT(v, r) (((v) << (r)) | ((v) >> (32 - (r))))
#define TFR(r) { x0 += x1; x1 = TFROT(x1, r); x1 ^= x0; }
  x0 += k0; x1 += k1;
  TFR(13) TFR(15) TFR(26) TFR(6)
  x0 += k1; x1 += k2 + 1u;
  TFR(17) TFR(29) TFR(16) TFR(24)
  x0 += k2; x1 += k0 + 2u;
  TFR(13) TFR(15) TFR(26) TFR(6)
  x0 += k0; x1 += k1 + 3u;
  TFR(17) TFR(29) TFR(16) TFR(24)
  x0 += k1; x1 += k2 + 4u;
  TFR(13) TFR(15) TFR(26) TFR(6)
  x0 += k2; x1 += k0 + 5u;
  o0 = x0; o1 = x1;
#undef TFR
#undef TFROT
}

__device__ inline bool keep_bit(uint32_t k0, uint32_t k1, uint32_t j) {
  uint32_t o0, o1;
  tf2x32(k0, k1, 0u, j, o0, o1);
  return (((o0 ^ o1) >> 31) == 0u);   // uniform<0.5 <=> MSB==0
}

// ---------- pass 1: per-(chunk,range) LDS histograms of dst and src ----------
__global__ __launch_bounds__(256) void hist_kernel(
    const int* __restrict__ src, const int* __restrict__ dst,
    uint32_t* __restrict__ slabD, uint32_t* __restrict__ slabS) {
  __shared__ uint32_t HD[RWORDS];
  __shared__ uint32_t HS[RWORDS];
  const int tid = threadIdx.x, b = blockIdx.x;
  const int c = b / NR, r = b - c * NR;
  const int e0 = c * EPB, e1 = e0 + EPB;
  const int nbase = r * RNODES;
  for (int w = tid; w < RWORDS; w += 256) { HD[w] = 0; HS[w] = 0; }
  __syncthreads();
  int e = e0 + tid;
  for (; e + 768 < e1; e += 1024) {
    int d0 = dst[e] - nbase,       d1 = dst[e + 256] - nbase;
    int d2 = dst[e + 512] - nbase, d3 = dst[e + 768] - nbase;
    int s0 = src[e] - nbase,       s1 = src[e + 256] - nbase;
    int s2 = src[e + 512] - nbase, s3 = src[e + 768] - nbase;
    if ((unsigned)d0 < (unsigned)RNODES) atomicAdd(&HD[d0 >> 1], 1u << ((d0 & 1) * 16));
    if ((unsigned)d1 < (unsigned)RNODES) atomicAdd(&HD[d1 >> 1], 1u << ((d1 & 1) * 16));
    if ((unsigned)d2 < (unsigned)RNODES) atomicAdd(&HD[d2 >> 1], 1u << ((d2 & 1) * 16));
    if ((unsigned)d3 < (unsigned)RNODES) atomicAdd(&HD[d3 >> 1], 1u << ((d3 & 1) * 16));
    if ((unsigned)s0 < (unsigned)RNODES) atomicAdd(&HS[s0 >> 1], 1u << ((s0 & 1) * 16));
    if ((unsigned)s1 < (unsigned)RNODES) atomicAdd(&HS[s1 >> 1], 1u << ((s1 & 1) * 16));
    if ((unsigned)s2 < (unsigned)RNODES) atomicAdd(&HS[s2 >> 1], 1u << ((s2 & 1) * 16));
    if ((unsigned)s3 < (unsigned)RNODES) atomicAdd(&HS[s3 >> 1], 1u << ((s3 & 1) * 16));
  }
  for (; e < e1; e += 256) {
    int d = dst[e] - nbase;
    if ((unsigned)d < (unsigned)RNODES) atomicAdd(&HD[d >> 1], 1u << ((d & 1) * 16));
    int s = src[e] - nbase;
    if ((unsigned)s < (unsigned)RNODES) atomicAdd(&HS[s >> 1], 1u << ((s & 1) * 16));
  }
  __syncthreads();
  uint32_t* dpD = slabD + (size_t)b * RWORDS;
  uint32_t* dpS = slabS + (size_t)b * RWORDS;
  for (int w = tid; w < RWORDS; w += 256) { dpD[w] = HD[w]; dpS[w] = HS[w]; }
}

// ---------- merged reduce + relative-base + inv: one stream over the slabs ----------
__global__ __launch_bounds__(256) void reduce_base_kernel(
    const uint32_t* __restrict__ slabD, const uint32_t* __restrict__ slabS,
    int* __restrict__ ideg, float* __restrict__ inv_o, float* __restrict__ inv_i,
    uint32_t* __restrict__ rel32) {
  int gw = blockIdx.x * 256 + threadIdx.x;
  if (gw >= NWORDS) return;
  int r = gw / RWORDS, lw = gw - r * RWORDS;
  int n0 = r * RNODES + 2 * lw;
  uint32_t runL = 0, runH = 0, lo = 0, ho = 0;
#pragma unroll 4
  for (int c = 0; c < NC; ++c) {
    rel32[(size_t)c * NWORDS + gw] = (runL & 0xFFFFu) | (runH << 16);
    uint32_t vi = slabD[(size_t)(c * NR + r) * RWORDS + lw];
    uint32_t vo = slabS[(size_t)(c * NR + r) * RWORDS + lw];
    runL += vi & 0xFFFFu; runH += vi >> 16;
    lo   += vo & 0xFFFFu; ho   += vo >> 16;
  }
  ideg[n0] = (int)runL; ideg[n0 + 1] = (int)runH;
  inv_i[n0]     = rsqrtf(fmaxf((float)runL, 1.0f));
  inv_i[n0 + 1] = rsqrtf(fmaxf((float)runH, 1.0f));
  inv_o[n0]     = rsqrtf(fmaxf((float)lo, 1.0f));
  inv_o[n0 + 1] = rsqrtf(fmaxf((float)ho, 1.0f));
}

// ---------- hierarchical exclusive scan of ideg -> row_ptr ----------
__global__ __launch_bounds__(256) void scan_blocks_kernel(
    const int* __restrict__ ideg, int* __restrict__ bsum) {
  __shared__ int lds[256];
  const int tid = threadIdx.x;
  int i = blockIdx.x * 256 + tid;
  lds[tid] = (i < NNODES) ? ideg[i] : 0;
  __syncthreads();
  for (int off = 128; off > 0; off >>= 1) {
    if (tid < off) lds[tid] += lds[tid + off];
    __syncthreads();
  }
  if (tid == 0) bsum[blockIdx.x] = lds[0];
}

__global__ __launch_bounds__(256) void scan_top_kernel(
    const int* __restrict__ bsum, int* __restrict__ boff) {
  __shared__ int lds[256];
  const int tid = threadIdx.x;
  int v = (tid < NB) ? bsum[tid] : 0;
  lds[tid] = v;
  __syncthreads();
  for (int off = 1; off < 256; off <<= 1) {
    int t = (tid >= off) ? lds[tid - off] : 0;
    __syncthreads();
    lds[tid] += t;
    __syncthreads();
  }
  if (tid < NB) boff[tid] = lds[tid] - v;   // exclusive
}

__global__ __launch_bounds__(256) void scan_write_kernel(
    const int* __restrict__ ideg, const int* __restrict__ boff,
    int* __restrict__ row_ptr) {
  __shared__ int lds[256];
  const int tid = threadIdx.x;
  int i = blockIdx.x * 256 + tid;
  int v = (i < NNODES) ? ideg[i] : 0;
  lds[tid] = v;
  __syncthreads();
  for (int off = 1; off < 256; off <<= 1) {
    int t = (tid >= off) ? lds[tid - off] : 0;
    __syncthreads();
    lds[tid] += t;
    __syncthreads();
  }
  if (i < NNODES) row_ptr[i] = boff[blockIdx.x] + lds[tid] - v;
  if (i == 0) row_ptr[NNODES] = NEDGES;
}

// ---------- pass 2: atomic-free CSR fill; packed weight = ew only ----------
__global__ __launch_bounds__(256) void fillh_kernel(
    const int* __restrict__ src, const int* __restrict__ dst, const float* __restrict__ ew,
    const uint32_t* __restrict__ rel32, const int* __restrict__ row_ptr,
    uint32_t* __restrict__ csr) {
  __shared__ uint32_t H[RWORDS];
  const int tid = threadIdx.x, b = blockIdx.x;
  const int c = b / NR, r = b - c * NR;
  const int e0 = c * EPB, e1 = e0 + EPB;
  const int nbase = r * RNODES;
  const uint32_t* rel = rel32 + (size_t)c * NWORDS;
  for (int w = tid; w < RWORDS; w += 256) H[w] = 0;
  __syncthreads();
  int e = e0 + tid;
  for (; e + 256 < e1; e += 512) {
    int da = dst[e], db = dst[e + 256];
    int sa = src[e], sb = src[e + 256];
    float wa = ew[e], wb = ew[e + 256];
    int la = da - nbase, lb = db - nbase;
    bool ia = (unsigned)la < (unsigned)RNODES;
    bool ib = (unsigned)lb < (unsigned)RNODES;
    if (ia) {
      int sh = (la & 1) * 16;
      uint32_t old = atomicAdd(&H[la >> 1], 1u << sh);
      int rank = (int)((old >> sh) & 0xFFFFu);
      int rel16 = (int)((rel[da >> 1] >> sh) & 0xFFFFu);
      int pos = row_ptr[da] + rel16 + rank;
      if ((unsigned)pos < (unsigned)NEDGES) {
        uint32_t v = ((uint32_t)sa << 16) | (uint32_t)__half_as_ushort(__float2half_rn(wa));
        __builtin_nontemporal_store(v, &csr[pos]);
      }
    }
    if (ib) {
      int sh = (lb & 1) * 16;
      uint32_t old = atomicAdd(&H[lb >> 1], 1u << sh);
      int rank = (int)((old >> sh) & 0xFFFFu);
      int rel16 = (int)((rel[db >> 1] >> sh) & 0xFFFFu);
      int pos = row_ptr[db] + rel16 + rank;
      if ((unsigned)pos < (unsigned)NEDGES) {
        uint32_t v = ((uint32_t)sb << 16) | (uint32_t)__half_as_ushort(__float2half_rn(wb));
        __builtin_nontemporal_store(v, &csr[pos]);
      }
    }
  }
  for (; e < e1; e += 256) {
    int d = dst[e];
    int ld = d - nbase;
    if ((unsigned)ld < (unsigned)RNODES) {
      int sh = (ld & 1) * 16;
      uint32_t old = atomicAdd(&H[ld >> 1], 1u << sh);
      int rank = (int)((old >> sh) & 0xFFFFu);
      int rel16 = (int)((rel[d >> 1] >> sh) & 0xFFFFu);
      int pos = row_ptr[d] + rel16 + rank;
      if ((unsigned)pos < (unsigned)NEDGES) {
        uint32_t v = ((uint32_t)src[e] << 16) | (uint32_t)__half_as_ushort(__float2half_rn(ew[e]));
        __builtin_nontemporal_store(v, &csr[pos]);
      }
    }
  }
}

// ---------- layer-0 dropout: mask * 2*inv_o (src-scale folded here) ----------
__global__ __launch_bounds__(256) void drop0_kernel(
    const float* __restrict__ h, const float* __restrict__ inv_o,
    float* __restrict__ X, uint32_t k0, uint32_t k1) {
  int j = blockIdx.x * 256 + threadIdx.x;
  if (j >= NNODES * NHID) return;
  int n = j / NHID;
  X[j] = keep_bit(k0, k1, (uint32_t)j) ? h[j] * (2.0f * inv_o[n]) : 0.0f;
}

// ---------- GEMM96: Yh[N,96](fp16) = X[N,96](fp32) @ W[96,96], LDS-staged W ----------
// thread tile = 8 rows x 12 cols (96 acc); block covers 256 rows.
// Per kk-step: 12 LDS floats feed 96 FMAs (8:1 vs old 4:1) -> half the ds_reads.
__global__ __launch_bounds__(256) void gemm96_kernel(
    const float* __restrict__ X, const float* __restrict__ W, __half* __restrict__ Yh) {
  __shared__ float Wl[96 * 96];
  const int tid = threadIdx.x;
  {
    const float4* Wg = (const float4*)W;
    float4* Ws = (float4*)Wl;
#pragma unroll
    for (int i = 0; i < 9; ++i)
      Ws[tid + i * 256] = Wg[tid + i * 256];
  }
  __syncthreads();

  const int cg = tid & 7;
  const int ro = tid >> 3;                 // 32 row-groups x 8 rows
  const int row0 = blockIdx.x * 256 + ro * 8;
  const int c0 = cg * 12;

  float acc[8][12];
#pragma unroll
  for (int r = 0; r < 8; ++r)
#pragma unroll
    for (int c = 0; c < 12; ++c) acc[r][c] = 0.f;

  const float* xr[8];
#pragma unroll
  for (int r = 0; r < 8; ++r) {
    int rr = row0 + r; if (rr > NNODES - 1) rr = NNODES - 1;
    xr[r] = X + (size_t)rr * 96;
  }

  for (int k = 0; k < 96; k += 4) {
    float4 x4[8];
#pragma unroll
    for (int r = 0; r < 8; ++r) x4[r] = *(const float4*)(xr[r] + k);
#pragma unroll
    for (int kk = 0; kk < 4; ++kk) {
      const float4* wp = (const float4*)(Wl + (k + kk) * 96 + c0);
      float4 w0 = wp[0], w1 = wp[1], w2 = wp[2];
#pragma unroll
      for (int r = 0; r < 8; ++r) {
        float xv = (&x4[r].x)[kk];
        acc[r][0]  += xv * w0.x; acc[r][1]  += xv * w0.y;
        acc[r][2]  += xv * w0.z; acc[r][3]  += xv * w0.w;
        acc[r][4]  += xv * w1.x; acc[r][5]  += xv * w1.y;
        acc[r][6]  += xv * w1.z; acc[r][7]  += xv * w1.w;
        acc[r][8]  += xv * w2.x; acc[r][9]  += xv * w2.y;
        acc[r][10] += xv * w2.z; acc[r][11] += xv * w2.w;
      }
    }
  }

#pragma unroll
  for (int r = 0; r < 8; ++r) {
    int rr = row0 + r;
    if (rr < NNODES) {
      __half2* hp = (__half2*)(Yh + (size_t)rr * 96 + c0);
#pragma unroll
      for (int c = 0; c < 6; ++c)
        hp[c] = __floats2half2_rn(acc[r][2 * c], acc[r][2 * c + 1]);
    }
  }
}

// ---------- GEMM16: Y2h[N,16](fp16) = X[N,96] @ W[96,16], LDS-staged W ----------
__global__ __launch_bounds__(256) void gemm16_kernel(
    const float* __restrict__ X, const float* __restrict__ W, __half* __restrict__ Y2h) {
  __shared__ float Wl[96 * 16];
  const int tid = threadIdx.x;
  {
    const float4* Wg = (const float4*)W;
    float4* Ws = (float4*)Wl;
    for (int i = tid; i < 384; i += 256) Ws[i] = Wg[i];
  }
  __syncthreads();

  const int row0 = blockIdx.x * 512 + tid * 2;
  const float* xr[2];
#pragma unroll
  for (int r = 0; r < 2; ++r) {
    int rr = row0 + r; if (rr > NNODES - 1) rr = NNODES - 1;
    xr[r] = X + (size_t)rr * 96;
  }

  float acc[2][16];
#pragma unroll
  for (int r = 0; r < 2; ++r)
#pragma unroll
    for (int c = 0; c < 16; ++c) acc[r][c] = 0.f;

  for (int k = 0; k < 96; k += 4) {
    float4 x4[2];
#pragma unroll
    for (int r = 0; r < 2; ++r) x4[r] = *(const float4*)(xr[r] + k);
#pragma unroll
    for (int kk = 0; kk < 4; ++kk) {
      const float4* wp = (const float4*)(Wl + (k + kk) * 16);
      float4 w0 = wp[0], w1 = wp[1], w2 = wp[2], w3 = wp[3];
#pragma unroll
      for (int r = 0; r < 2; ++r) {
        float xv = (&x4[r].x)[kk];
        acc[r][0]  += xv * w0.x; acc[r][1]  += xv * w0.y;
        acc[r][2]  += xv * w0.z; acc[r][3]  += xv * w0.w;
        acc[r][4]  += xv * w1.x; acc[r][5]  += xv * w1.y;
        acc[r][6]  += xv * w1.z; acc[r][7]  += xv * w1.w;
        acc[r][8]  += xv * w2.x; acc[r][9]  += xv * w2.y;
        acc[r][10] += xv * w2.z; acc[r][11] += xv * w2.w;
        acc[r][12] += xv * w3.x; acc[r][13] += xv * w3.y;
        acc[r][14] += xv * w3.z; acc[r][15] += xv * w3.w;
      }
    }
  }

#pragma unroll
  for (int r = 0; r < 2; ++r) {
    int rr = row0 + r;
    if (rr < NNODES) {
      __half2* hp = (__half2*)(Y2h + (size_t)rr * 16);
#pragma unroll
      for (int c = 0; c < 8; ++c)
        hp[c] = __floats2half2_rn(acc[r][2 * c], acc[r][2 * c + 1]);
    }
  }
}

// ---------- CSR gather (fp16 Y) + inv_in*bias + ReLU + dropout + 2*inv_o ----------
#define ACC16(u0, u1, wt) { \
  float2 g0 = __half22float2(*(__half2*)&u0.x); \
  float2 g1 = __half22float2(*(__half2*)&u0.y); \
  float2 g2 = __half22float2(*(__half2*)&u0.z); \
  float2 g3 = __half22float2(*(__half2*)&u0.w); \
  float2 g4 = __half22float2(*(__half2*)&u1.x); \
  float2 g5 = __half22float2(*(__half2*)&u1.y); \
  float2 g6 = __half22float2(*(__half2*)&u1.z); \
  float2 g7 = __half22float2(*(__half2*)&u1.w); \
  acc[0]  += g0.x * wt; acc[1]  += g0.y * wt; \
  acc[2]  += g1.x * wt; acc[3]  += g1.y * wt; \
  acc[4]  += g2.x * wt; acc[5]  += g2.y * wt; \
  acc[6]  += g3.x * wt; acc[7]  += g3.y * wt; \
  acc[8]  += g4.x * wt; acc[9]  += g4.y * wt; \
  acc[10] += g5.x * wt; acc[11] += g5.y * wt; \
  acc[12] += g6.x * wt; acc[13] += g6.y * wt; \
  acc[14] += g7.x * wt; acc[15] += g7.y * wt; }

__global__ __launch_bounds__(256) void gather96_drop_kernel(
    const __half* __restrict__ Yh, const uint32_t* __restrict__ csr,
    const int* __restrict__ row_ptr, const float* __restrict__ inv_in,
    const float* __restrict__ inv_o, const float* __restrict__ bias,
    float* __restrict__ Xn, uint32_t k0, uint32_t k1) {
  int tid = blockIdx.x * 256 + threadIdx.x;
  int n = tid / 6;
  int q = tid - n * 6;        // 16-dim chunk within the 96-dim row
  if (n >= NNODES) return;
  int beg = row_ptr[n], end = row_ptr[n + 1];
  float acc[16];
#pragma unroll
  for (int i = 0; i < 16; ++i) acc[i] = 0.f;

  int p = beg;
  // 4-edge unroll: 8 independent uint4 loads in flight per lane
  for (; p + 4 <= end; p += 4) {
    uint32_t pa = csr[p], pb = csr[p + 1], pc = csr[p + 2], pd = csr[p + 3];
    int s0 = pa >> 16, s1 = pb >> 16, s2 = pc >> 16, s3 = pd >> 16;
    if (s0 >= NNODES) s0 = 0;
    if (s1 >= NNODES) s1 = 0;
    if (s2 >= NNODES) s2 = 0;
    if (s3 >= NNODES) s3 = 0;
    float w0 = __half2float(__ushort_as_half((unsigned short)(pa & 0xFFFFu)));
    float w1 = __half2float(__ushort_as_half((unsigned short)(pb & 0xFFFFu)));
    float w2 = __half2float(__ushort_as_half((unsigned short)(pc & 0xFFFFu)));
    float w3 = __half2float(__ushort_as_half((unsigned short)(pd & 0xFFFFu)));
    const uint4* y0 = (const uint4*)(Yh + (size_t)s0 * 96 + q * 16);
    const uint4* y1 = (const uint4*)(Yh + (size_t)s1 * 96 + q * 16);
    const uint4* y2 = (const uint4*)(Yh + (size_t)s2 * 96 + q * 16);
    const uint4* y3 = (const uint4*)(Yh + (size_t)s3 * 96 + q * 16);
    uint4 a0 = y0[0], a1 = y0[1];
    uint4 b0 = y1[0], b1 = y1[1];
    uint4 c0 = y2[0], c1 = y2[1];
    uint4 d0 = y3[0], d1 = y3[1];
    ACC16(a0, a1, w0)
    ACC16(b0, b1, w1)
    ACC16(c0, c1, w2)
    ACC16(d0, d1, w3)
  }
  for (; p + 2 <= end; p += 2) {
    uint32_t pa = csr[p], pb = csr[p + 1];
    int s0 = pa >> 16, s1 = pb >> 16;
    if (s0 >= NNODES) s0 = 0;
    if (s1 >= NNODES) s1 = 0;
    float w0 = __half2float(__ushort_as_half((unsigned short)(pa & 0xFFFFu)));
    float w1 = __half2float(__ushort_as_half((unsigned short)(pb & 0xFFFFu)));
    const uint4* y0 = (const uint4*)(Yh + (size_t)s0 * 96 + q * 16);
    const uint4* y1 = (const uint4*)(Yh + (size_t)s1 * 96 + q * 16);
    uint4 a0 = y0[0], a1 = y0[1];
    uint4 b0 = y1[0], b1 = y1[1];
    ACC16(a0, a1, w0)
    ACC16(b0, b1, w1)
  }
  if (p < end) {
    uint32_t pa = csr[p];
    int s0 = pa >> 16;
    if (s0 >= NNODES) s0 = 0;
    float w0 = __half2float(__ushort_as_half((unsigned short)(pa & 0xFFFFu)));
    const uint4* y0 = (const uint4*)(Yh + (size_t)s0 * 96 + q * 16);
    uint4 a0 = y0[0], a1 = y0[1];
    ACC16(a0, a1, w0)
  }

  float iv = inv_in[n];
  float sc = 2.0f * inv_o[n];            // next-layer src scale, folded here
  const float* bp = bias + q * 16;
  float o[16];
#pragma unroll
  for (int i = 0; i < 16; ++i)
    o[i] = fmaxf(acc[i] * iv + bp[i], 0.f) * sc;
  uint32_t jb = (uint32_t)(n * 96 + q * 16);
#pragma unroll
  for (int i = 0; i < 16; ++i)
    o[i] = keep_bit(k0, k1, jb + i) ? o[i] : 0.f;
  float* xp = Xn + (size_t)n * 96 + q * 16;
  *(float4*)(xp + 0)  = make_float4(o[0], o[1], o[2], o[3]);
  *(float4*)(xp + 4)  = make_float4(o[4], o[5], o[6], o[7]);
  *(float4*)(xp + 8)  = make_float4(o[8], o[9], o[10], o[11]);
  *(float4*)(xp + 12) = make_float4(o[12], o[13], o[14], o[15]);
}

// ---------- layer 2: CSR gather (fp16 Y2) + bias + log_softmax, 2-edge unroll ----------
__global__ __launch_bounds__(256) void gather16_lsm_kernel(
    const __half* __restrict__ Y2h, const uint32_t* __restrict__ csr,
    const int* __restrict__ row_ptr, const float* __restrict__ inv_in,
    const float* __restrict__ b2, float* __restrict__ out) {
  int n = blockIdx.x * 256 + threadIdx.x;
  if (n >= NNODES) return;
  int beg = row_ptr[n], end = row_ptr[n + 1];
  float acc[16];
#pragma unroll
  for (int i = 0; i < 16; ++i) acc[i] = 0.f;

  int p = beg;
  for (; p + 2 <= end; p += 2) {
    uint32_t pa = csr[p], pb = csr[p + 1];
    int sa = pa >> 16, sb = pb >> 16;
    if (sa >= NNODES) sa = 0;
    if (sb >= NNODES) sb = 0;
    float wa = __half2float(__ushort_as_half((unsigned short)(pa & 0xFFFFu)));
    float wb = __half2float(__ushort_as_half((unsigned short)(pb & 0xFFFFu)));
    const uint4* ya = (const uint4*)(Y2h + (size_t)sa * 16);
    const uint4* yb = (const uint4*)(Y2h + (size_t)sb * 16);
    uint4 a0 = ya[0], a1 = ya[1];
    uint4 b0 = yb[0], b1 = yb[1];
    ACC16(a0, a1, wa)
    ACC16(b0, b1, wb)
  }
  if (p < end) {
    uint32_t pa = csr[p];
    int sa = pa >> 16;
    if (sa >= NNODES) sa = 0;
    float wa = __half2float(__ushort_as_half((unsigned short)(pa & 0xFFFFu)));
    const uint4* ya = (const uint4*)(Y2h + (size_t)sa * 16);
    uint4 a0 = ya[0], a1 = ya[1];
    ACC16(a0, a1, wa)
  }

  float iv = inv_in[n];
  float v[16];
#pragma unroll
  for (int i = 0; i < 16; ++i) v[i] = acc[i] * iv + b2[i];
  float m = v[0];
#pragma unroll
  for (int i = 1; i < 16; i++) m = fmaxf(m, v[i]);
  float s = 0.f;
#pragma unroll
  for (int i = 0; i < 16; i++) s += expf(v[i] - m);
  float ls = logf(s);
  float* orow = out + (size_t)n * 16;
#pragma unroll
  for (int i = 0; i < 16; i++) orow[i] = v[i] - m - ls;
}

extern "C" void kernel_launch(void* const* d_in, const int* in_sizes, int n_in,
                              void* d_out, int out_size, void* d_ws, size_t ws_size,
                              hipStream_t stream) {
  const float* feat = (const float*)d_in[0];
  const float* ew   = (const float*)d_in[1];
  const int*   src  = (const int*)d_in[2];
  const int*   dst  = (const int*)d_in[3];
  const float* W0   = (const float*)d_in[4];
  const float* b0   = (const float*)d_in[5];
  const float* W1   = (const float*)d_in[6];
  const float* b1   = (const float*)d_in[7];
  const float* W2   = (const float*)d_in[8];
  const float* b2   = (const float*)d_in[9];
  float* out = (float*)d_out;

  char* base = (char*)d_ws;
  size_t off = 0;
  auto take = [&](size_t nbytes) {
    void* q = base + off;
    off += (nbytes + 255) & ~(size_t)255;
    return q;
  };
  int*      ideg    = (int*)take((size_t)NNODES * 4);
  int*      row_ptr = (int*)take((size_t)(NNODES + 1) * 4);
  int*      bsum    = (int*)take((size_t)NB * 4);
  int*      boff    = (int*)take((size_t)NB * 4);
  float*    inv_o   = (float*)take((size_t)NNODES * 4);
  float*    inv_i   = (float*)take((size_t)NNODES * 4);
  uint32_t* slabD   = (uint32_t*)take((size_t)NC * NR * RWORDS * 4);  // 20 MB
  uint32_t* slabS   = (uint32_t*)take((size_t)NC * NR * RWORDS * 4);  // 20 MB
  uint32_t* rel32   = (uint32_t*)take((size_t)NC * NWORDS * 4);       // 20 MB
  uint32_t* csr     = (uint32_t*)take((size_t)NEDGES * 4);
  float*    X       = (float*)take((size_t)NNODES * NHID * 4);
  __half*   Yh      = (__half*)take((size_t)NNODES * NHID * 2);
  __half*   Y2h     = (__half*)take((size_t)NNODES * NCLS * 2);
  (void)ws_size; (void)in_sizes; (void)n_in; (void)out_size;

  uint32_t k[3][2];
  for (uint32_t i = 0; i < 3; i++) tf2x32(0u, 42u, 0u, i, k[i][0], k[i][1]);

  const int GW = (NWORDS + 255) / 256;   // 98 blocks for word-indexed kernels

  // graph build: atomic-free, grid = NC*NR = 800 (~3 blocks/CU).
  // (csr memset dropped: fill provably writes a complete permutation of [0,NEDGES);
  //  decode-side guards remain as containment.)
  hist_kernel<<<NC * NR, 256, 0, stream>>>(src, dst, slabD, slabS);
  reduce_base_kernel<<<GW, 256, 0, stream>>>(slabD, slabS, ideg, inv_o, inv_i, rel32);
  scan_blocks_kernel<<<NB, 256, 0, stream>>>(ideg, bsum);
  scan_top_kernel<<<1, 256, 0, stream>>>(bsum, boff);
  scan_write_kernel<<<NB, 256, 0, stream>>>(ideg, boff, row_ptr);
  fillh_kernel<<<NC * NR, 256, 0, stream>>>(src, dst, ew, rel32, row_ptr, csr);

  const int NELEM = NNODES * NHID;
  const int G96  = (NNODES + 255) / 256;   // 196 blocks (256 rows/block)
  const int G16  = (NNODES + 511) / 512;
  const int GGD  = (NNODES * 6 + 255) / 256;

  // layer 0: feat --mask0*2inv_o--> X --gemm--> Yh --gather+mask1*2inv_o--> X
  drop0_kernel<<<(NELEM + 255) / 256, 256, 0, stream>>>(feat, inv_o, X, k[0][0], k[0][1]);
  gemm96_kernel<<<G96, 256, 0, stream>>>(X, W0, Yh);
  gather96_drop_kernel<<<GGD, 256, 0, stream>>>(Yh, csr, row_ptr, inv_i, inv_o, b0, X, k[1][0], k[1][1]);
  // layer 1: X --gemm--> Yh --gather+mask2*2inv_o--> X
  gemm96_kernel<<<G96, 256, 0, stream>>>(X, W1, Yh);
  gather96_drop_kernel<<<GGD, 256, 0, stream>>>(Yh, csr, row_ptr, inv_i, inv_o, b1, X, k[2][0], k[2][1]);
  // layer 2: X --gemm16--> Y2h --gather+lsm--> out
  gemm16_kernel<<<G16, 256, 0, stream>>>(X, W2, Y2h);
  gather16_lsm_kernel<<<(NNODES + 255) / 256, 256, 0, stream>>>(Y2h, csr, row_ptr, inv_i, b2, out);
}

// Round 14
// 310.903 us; speedup vs baseline: 1.0715x; 1.0715x over previous
//
#include <hip/hip_runtime.h>
#include <hip/hip_fp16.h>
#include <stdint.h>

#define NNODES 50000
#define NEDGES 800000
#define NHID 96
#define NCLS 16
#define NB ((NNODES + 255) / 256)   // 196 scan blocks

// graph build: NC edge-chunks x NR node-ranges; per-block LDS histogram of one
// range (12500 nodes, u16 pair-packed into 6250 u32 words). grid = NC*NR = 800.
#define NC 200
#define NR 4
#define EPB (NEDGES / NC)           // 4000 edges per chunk
#define RNODES (NNODES / NR)        // 12500 nodes per range
#define RWORDS (RNODES / 2)         // 6250 packed words
#define NWORDS (NNODES / 2)         // 25000 global packed words

// ---------- JAX Threefry-2x32 (Random123 20-round, matches jax._src.prng) ----------
__host__ __device__ inline void tf2x32(uint32_t k0, uint32_t k1, uint32_t x0, uint32_t x1,
                                       uint32_t& o0, uint32_t& o1) {
  uint32_t k2 = k0 ^ k1 ^ 0x1BD11BDAu;
#define TFROT(v, r) (((v) << (r)) | ((v) >> (32 - (r))))
#define TFR(r) { x0 += x1; x1 = TFROT(x1, r); x1 ^= x0; }
  x0 += k0; x1 += k1;
  TFR(13) TFR(15) TFR(26) TFR(6)
  x0 += k1; x1 += k2 + 1u;
  TFR(17) TFR(29) TFR(16) TFR(24)
  x0 += k2; x1 += k0 + 2u;
  TFR(13) TFR(15) TFR(26) TFR(6)
  x0 += k0; x1 += k1 + 3u;
  TFR(17) TFR(29) TFR(16) TFR(24)
  x0 += k1; x1 += k2 + 4u;
  TFR(13) TFR(15) TFR(26) TFR(6)
  x0 += k2; x1 += k0 + 5u;
  o0 = x0; o1 = x1;
#undef TFR
#undef TFROT
}

__device__ inline bool keep_bit(uint32_t k0, uint32_t k1, uint32_t j) {
  uint32_t o0, o1;
  tf2x32(k0, k1, 0u, j, o0, o1);
  return (((o0 ^ o1) >> 31) == 0u);   // uniform<0.5 <=> MSB==0
}

// ---------- pass 1: per-(chunk,range) LDS histograms of dst and src ----------
__global__ __launch_bounds__(256) void hist_kernel(
    const int* __restrict__ src, const int* __restrict__ dst,
    uint32_t* __restrict__ slabD, uint32_t* __restrict__ slabS) {
  __shared__ uint32_t HD[RWORDS];
  __shared__ uint32_t HS[RWORDS];
  const int tid = threadIdx.x, b = blockIdx.x;
  const int c = b / NR, r = b - c * NR;
  const int e0 = c * EPB, e1 = e0 + EPB;
  const int nbase = r * RNODES;
  for (int w = tid; w < RWORDS; w += 256) { HD[w] = 0; HS[w] = 0; }
  __syncthreads();
  int e = e0 + tid;
  for (; e + 768 < e1; e += 1024) {
    int d0 = dst[e] - nbase,       d1 = dst[e + 256] - nbase;
    int d2 = dst[e + 512] - nbase, d3 = dst[e + 768] - nbase;
    int s0 = src[e] - nbase,       s1 = src[e + 256] - nbase;
    int s2 = src[e + 512] - nbase, s3 = src[e + 768] - nbase;
    if ((unsigned)d0 < (unsigned)RNODES) atomicAdd(&HD[d0 >> 1], 1u << ((d0 & 1) * 16));
    if ((unsigned)d1 < (unsigned)RNODES) atomicAdd(&HD[d1 >> 1], 1u << ((d1 & 1) * 16));
    if ((unsigned)d2 < (unsigned)RNODES) atomicAdd(&HD[d2 >> 1], 1u << ((d2 & 1) * 16));
    if ((unsigned)d3 < (unsigned)RNODES) atomicAdd(&HD[d3 >> 1], 1u << ((d3 & 1) * 16));
    if ((unsigned)s0 < (unsigned)RNODES) atomicAdd(&HS[s0 >> 1], 1u << ((s0 & 1) * 16));
    if ((unsigned)s1 < (unsigned)RNODES) atomicAdd(&HS[s1 >> 1], 1u << ((s1 & 1) * 16));
    if ((unsigned)s2 < (unsigned)RNODES) atomicAdd(&HS[s2 >> 1], 1u << ((s2 & 1) * 16));
    if ((unsigned)s3 < (unsigned)RNODES) atomicAdd(&HS[s3 >> 1], 1u << ((s3 & 1) * 16));
  }
  for (; e < e1; e += 256) {
    int d = dst[e] - nbase;
    if ((unsigned)d < (unsigned)RNODES) atomicAdd(&HD[d >> 1], 1u << ((d & 1) * 16));
    int s = src[e] - nbase;
    if ((unsigned)s < (unsigned)RNODES) atomicAdd(&HS[s >> 1], 1u << ((s & 1) * 16));
  }
  __syncthreads();
  uint32_t* dpD = slabD + (size_t)b * RWORDS;
  uint32_t* dpS = slabS + (size_t)b * RWORDS;
  for (int w = tid; w < RWORDS; w += 256) { dpD[w] = HD[w]; dpS[w] = HS[w]; }
}

// ---------- merged reduce + relative-base + inv: one stream over the slabs ----------
__global__ __launch_bounds__(256) void reduce_base_kernel(
    const uint32_t* __restrict__ slabD, const uint32_t* __restrict__ slabS,
    int* __restrict__ ideg, float* __restrict__ inv_o, float* __restrict__ inv_i,
    uint32_t* __restrict__ rel32) {
  int gw = blockIdx.x * 256 + threadIdx.x;
  if (gw >= NWORDS) return;
  int r = gw / RWORDS, lw = gw - r * RWORDS;
  int n0 = r * RNODES + 2 * lw;
  uint32_t runL = 0, runH = 0, lo = 0, ho = 0;
#pragma unroll 4
  for (int c = 0; c < NC; ++c) {
    rel32[(size_t)c * NWORDS + gw] = (runL & 0xFFFFu) | (runH << 16);
    uint32_t vi = slabD[(size_t)(c * NR + r) * RWORDS + lw];
    uint32_t vo = slabS[(size_t)(c * NR + r) * RWORDS + lw];
    runL += vi & 0xFFFFu; runH += vi >> 16;
    lo   += vo & 0xFFFFu; ho   += vo >> 16;
  }
  ideg[n0] = (int)runL; ideg[n0 + 1] = (int)runH;
  inv_i[n0]     = rsqrtf(fmaxf((float)runL, 1.0f));
  inv_i[n0 + 1] = rsqrtf(fmaxf((float)runH, 1.0f));
  inv_o[n0]     = rsqrtf(fmaxf((float)lo, 1.0f));
  inv_o[n0 + 1] = rsqrtf(fmaxf((float)ho, 1.0f));
}

// ---------- hierarchical exclusive scan of ideg -> row_ptr ----------
__global__ __launch_bounds__(256) void scan_blocks_kernel(
    const int* __restrict__ ideg, int* __restrict__ bsum) {
  __shared__ int lds[256];
  const int tid = threadIdx.x;
  int i = blockIdx.x * 256 + tid;
  lds[tid] = (i < NNODES) ? ideg[i] : 0;
  __syncthreads();
  for (int off = 128; off > 0; off >>= 1) {
    if (tid < off) lds[tid] += lds[tid + off];
    __syncthreads();
  }
  if (tid == 0) bsum[blockIdx.x] = lds[0];
}

__global__ __launch_bounds__(256) void scan_top_kernel(
    const int* __restrict__ bsum, int* __restrict__ boff) {
  __shared__ int lds[256];
  const int tid = threadIdx.x;
  int v = (tid < NB) ? bsum[tid] : 0;
  lds[tid] = v;
  __syncthreads();
  for (int off = 1; off < 256; off <<= 1) {
    int t = (tid >= off) ? lds[tid - off] : 0;
    __syncthreads();
    lds[tid] += t;
    __syncthreads();
  }
  if (tid < NB) boff[tid] = lds[tid] - v;   // exclusive
}

__global__ __launch_bounds__(256) void scan_write_kernel(
    const int* __restrict__ ideg, const int* __restrict__ boff,
    int* __restrict__ row_ptr) {
  __shared__ int lds[256];
  const int tid = threadIdx.x;
  int i = blockIdx.x * 256 + tid;
  int v = (i < NNODES) ? ideg[i] : 0;
  lds[tid] = v;
  __syncthreads();
  for (int off = 1; off < 256; off <<= 1) {
    int t = (tid >= off) ? lds[tid - off] : 0;
    __syncthreads();
    lds[tid] += t;
    __syncthreads();
  }
  if (i < NNODES) row_ptr[i] = boff[blockIdx.x] + lds[tid] - v;
  if (i == 0) row_ptr[NNODES] = NEDGES;
}

// ---------- pass 2: atomic-free CSR fill; packed weight = ew only ----------
__global__ __launch_bounds__(256) void fillh_kernel(
    const int* __restrict__ src, const int* __restrict__ dst, const float* __restrict__ ew,
    const uint32_t* __restrict__ rel32, const int* __restrict__ row_ptr,
    uint32_t* __restrict__ csr) {
  __shared__ uint32_t H[RWORDS];
  const int tid = threadIdx.x, b = blockIdx.x;
  const int c = b / NR, r = b - c * NR;
  const int e0 = c * EPB, e1 = e0 + EPB;
  const int nbase = r * RNODES;
  const uint32_t* rel = rel32 + (size_t)c * NWORDS;
  for (int w = tid; w < RWORDS; w += 256) H[w] = 0;
  __syncthreads();
  int e = e0 + tid;
  for (; e + 256 < e1; e += 512) {
    int da = dst[e], db = dst[e + 256];
    int sa = src[e], sb = src[e + 256];
    float wa = ew[e], wb = ew[e + 256];
    int la = da - nbase, lb = db - nbase;
    bool ia = (unsigned)la < (unsigned)RNODES;
    bool ib = (unsigned)lb < (unsigned)RNODES;
    if (ia) {
      int sh = (la & 1) * 16;
      uint32_t old = atomicAdd(&H[la >> 1], 1u << sh);
      int rank = (int)((old >> sh) & 0xFFFFu);
      int rel16 = (int)((rel[da >> 1] >> sh) & 0xFFFFu);
      int pos = row_ptr[da] + rel16 + rank;
      if ((unsigned)pos < (unsigned)NEDGES) {
        uint32_t v = ((uint32_t)sa << 16) | (uint32_t)__half_as_ushort(__float2half_rn(wa));
        __builtin_nontemporal_store(v, &csr[pos]);
      }
    }
    if (ib) {
      int sh = (lb & 1) * 16;
      uint32_t old = atomicAdd(&H[lb >> 1], 1u << sh);
      int rank = (int)((old >> sh) & 0xFFFFu);
      int rel16 = (int)((rel[db >> 1] >> sh) & 0xFFFFu);
      int pos = row_ptr[db] + rel16 + rank;
      if ((unsigned)pos < (unsigned)NEDGES) {
        uint32_t v = ((uint32_t)sb << 16) | (uint32_t)__half_as_ushort(__float2half_rn(wb));
        __builtin_nontemporal_store(v, &csr[pos]);
      }
    }
  }
  for (; e < e1; e += 256) {
    int d = dst[e];
    int ld = d - nbase;
    if ((unsigned)ld < (unsigned)RNODES) {
      int sh = (ld & 1) * 16;
      uint32_t old = atomicAdd(&H[ld >> 1], 1u << sh);
      int rank = (int)((old >> sh) & 0xFFFFu);
      int rel16 = (int)((rel[d >> 1] >> sh) & 0xFFFFu);
      int pos = row_ptr[d] + rel16 + rank;
      if ((unsigned)pos < (unsigned)NEDGES) {
        uint32_t v = ((uint32_t)src[e] << 16) | (uint32_t)__half_as_ushort(__float2half_rn(ew[e]));
        __builtin_nontemporal_store(v, &csr[pos]);
      }
    }
  }
}

// ---------- layer-0 dropout: mask * 2*inv_o (src-scale folded here) ----------
__global__ __launch_bounds__(256) void drop0_kernel(
    const float* __restrict__ h, const float* __restrict__ inv_o,
    float* __restrict__ X, uint32_t k0, uint32_t k1) {
  int j = blockIdx.x * 256 + threadIdx.x;
  if (j >= NNODES * NHID) return;
  int n = j / NHID;
  X[j] = keep_bit(k0, k1, (uint32_t)j) ? h[j] * (2.0f * inv_o[n]) : 0.0f;
}

// ---------- GEMM96: Yh[N,96](fp16) = X[N,96](fp32) @ W[96,96], LDS-staged W ----------
// thread tile = 4 rows x 12 cols (proven round-12 shape; 8x12 regressed via VGPR).
__global__ __launch_bounds__(256) void gemm96_kernel(
    const float* __restrict__ X, const float* __restrict__ W, __half* __restrict__ Yh) {
  __shared__ float Wl[96 * 96];
  const int tid = threadIdx.x;
  {
    const float4* Wg = (const float4*)W;
    float4* Ws = (float4*)Wl;
#pragma unroll
    for (int i = 0; i < 9; ++i)
      Ws[tid + i * 256] = Wg[tid + i * 256];
  }
  __syncthreads();

  const int cg = tid & 7;
  const int rq = tid >> 3;
  const int row0 = blockIdx.x * 128 + rq * 4;
  const int c0 = cg * 12;

  float acc[4][12];
#pragma unroll
  for (int r = 0; r < 4; ++r)
#pragma unroll
    for (int c = 0; c < 12; ++c) acc[r][c] = 0.f;

  const float* xr[4];
#pragma unroll
  for (int r = 0; r < 4; ++r) {
    int rr = row0 + r; if (rr > NNODES - 1) rr = NNODES - 1;
    xr[r] = X + (size_t)rr * 96;
  }

  for (int k = 0; k < 96; k += 4) {
    float4 x4[4];
#pragma unroll
    for (int r = 0; r < 4; ++r) x4[r] = *(const float4*)(xr[r] + k);
#pragma unroll
    for (int kk = 0; kk < 4; ++kk) {
      const float4* wp = (const float4*)(Wl + (k + kk) * 96 + c0);
      float4 w0 = wp[0], w1 = wp[1], w2 = wp[2];
      float xv[4] = { (&x4[0].x)[kk], (&x4[1].x)[kk], (&x4[2].x)[kk], (&x4[3].x)[kk] };
#pragma unroll
      for (int r = 0; r < 4; ++r) {
        acc[r][0]  += xv[r] * w0.x; acc[r][1]  += xv[r] * w0.y;
        acc[r][2]  += xv[r] * w0.z; acc[r][3]  += xv[r] * w0.w;
        acc[r][4]  += xv[r] * w1.x; acc[r][5]  += xv[r] * w1.y;
        acc[r][6]  += xv[r] * w1.z; acc[r][7]  += xv[r] * w1.w;
        acc[r][8]  += xv[r] * w2.x; acc[r][9]  += xv[r] * w2.y;
        acc[r][10] += xv[r] * w2.z; acc[r][11] += xv[r] * w2.w;
      }
    }
  }

#pragma unroll
  for (int r = 0; r < 4; ++r) {
    int rr = row0 + r;
    if (rr < NNODES) {
      __half2* hp = (__half2*)(Yh + (size_t)rr * 96 + c0);
#pragma unroll
      for (int c = 0; c < 6; ++c)
        hp[c] = __floats2half2_rn(acc[r][2 * c], acc[r][2 * c + 1]);
    }
  }
}

// ---------- GEMM16: Y2h[N,16](fp16) = X[N,96] @ W[96,16], LDS-staged W ----------
__global__ __launch_bounds__(256) void gemm16_kernel(
    const float* __restrict__ X, const float* __restrict__ W, __half* __restrict__ Y2h) {
  __shared__ float Wl[96 * 16];
  const int tid = threadIdx.x;
  {
    const float4* Wg = (const float4*)W;
    float4* Ws = (float4*)Wl;
    for (int i = tid; i < 384; i += 256) Ws[i] = Wg[i];
  }
  __syncthreads();

  const int row0 = blockIdx.x * 512 + tid * 2;
  const float* xr[2];
#pragma unroll
  for (int r = 0; r < 2; ++r) {
    int rr = row0 + r; if (rr > NNODES - 1) rr = NNODES - 1;
    xr[r] = X + (size_t)rr * 96;
  }

  float acc[2][16];
#pragma unroll
  for (int r = 0; r < 2; ++r)
#pragma unroll
    for (int c = 0; c < 16; ++c) acc[r][c] = 0.f;

  for (int k = 0; k < 96; k += 4) {
    float4 x4[2];
#pragma unroll
    for (int r = 0; r < 2; ++r) x4[r] = *(const float4*)(xr[r] + k);
#pragma unroll
    for (int kk = 0; kk < 4; ++kk) {
      const float4* wp = (const float4*)(Wl + (k + kk) * 16);
      float4 w0 = wp[0], w1 = wp[1], w2 = wp[2], w3 = wp[3];
#pragma unroll
      for (int r = 0; r < 2; ++r) {
        float xv = (&x4[r].x)[kk];
        acc[r][0]  += xv * w0.x; acc[r][1]  += xv * w0.y;
        acc[r][2]  += xv * w0.z; acc[r][3]  += xv * w0.w;
        acc[r][4]  += xv * w1.x; acc[r][5]  += xv * w1.y;
        acc[r][6]  += xv * w1.z; acc[r][7]  += xv * w1.w;
        acc[r][8]  += xv * w2.x; acc[r][9]  += xv * w2.y;
        acc[r][10] += xv * w2.z; acc[r][11] += xv * w2.w;
        acc[r][12] += xv * w3.x; acc[r][13] += xv * w3.y;
        acc[r][14] += xv * w3.z; acc[r][15] += xv * w3.w;
      }
    }
  }

#pragma unroll
  for (int r = 0; r < 2; ++r) {
    int rr = row0 + r;
    if (rr < NNODES) {
      __half2* hp = (__half2*)(Y2h + (size_t)rr * 16);
#pragma unroll
      for (int c = 0; c < 8; ++c)
        hp[c] = __floats2half2_rn(acc[r][2 * c], acc[r][2 * c + 1]);
    }
  }
}

// ---------- CSR gather (fp16 Y) + inv_in*bias + ReLU + dropout + 2*inv_o ----------
#define ACC16(u0, u1, wt) { \
  float2 g0 = __half22float2(*(__half2*)&u0.x); \
  float2 g1 = __half22float2(*(__half2*)&u0.y); \
  float2 g2 = __half22float2(*(__half2*)&u0.z); \
  float2 g3 = __half22float2(*(__half2*)&u0.w); \
  float2 g4 = __half22float2(*(__half2*)&u1.x); \
  float2 g5 = __half22float2(*(__half2*)&u1.y); \
  float2 g6 = __half22float2(*(__half2*)&u1.z); \
  float2 g7 = __half22float2(*(__half2*)&u1.w); \
  acc[0]  += g0.x * wt; acc[1]  += g0.y * wt; \
  acc[2]  += g1.x * wt; acc[3]  += g1.y * wt; \
  acc[4]  += g2.x * wt; acc[5]  += g2.y * wt; \
  acc[6]  += g3.x * wt; acc[7]  += g3.y * wt; \
  acc[8]  += g4.x * wt; acc[9]  += g4.y * wt; \
  acc[10] += g5.x * wt; acc[11] += g5.y * wt; \
  acc[12] += g6.x * wt; acc[13] += g6.y * wt; \
  acc[14] += g7.x * wt; acc[15] += g7.y * wt; }

__global__ __launch_bounds__(256) void gather96_drop_kernel(
    const __half* __restrict__ Yh, const uint32_t* __restrict__ csr,
    const int* __restrict__ row_ptr, const float* __restrict__ inv_in,
    const float* __restrict__ inv_o, const float* __restrict__ bias,
    float* __restrict__ Xn, uint32_t k0, uint32_t k1) {
  int tid = blockIdx.x * 256 + threadIdx.x;
  int n = tid / 6;
  int q = tid - n * 6;        // 16-dim chunk within the 96-dim row
  if (n >= NNODES) return;
  int beg = row_ptr[n], end = row_ptr[n + 1];
  float acc[16];
#pragma unroll
  for (int i = 0; i < 16; ++i) acc[i] = 0.f;

  int p = beg;
  // 4-edge unroll: 8 independent uint4 loads in flight per lane
  for (; p + 4 <= end; p += 4) {
    uint32_t pa = csr[p], pb = csr[p + 1], pc = csr[p + 2], pd = csr[p + 3];
    int s0 = pa >> 16, s1 = pb >> 16, s2 = pc >> 16, s3 = pd >> 16;
    if (s0 >= NNODES) s0 = 0;
    if (s1 >= NNODES) s1 = 0;
    if (s2 >= NNODES) s2 = 0;
    if (s3 >= NNODES) s3 = 0;
    float w0 = __half2float(__ushort_as_half((unsigned short)(pa & 0xFFFFu)));
    float w1 = __half2float(__ushort_as_half((unsigned short)(pb & 0xFFFFu)));
    float w2 = __half2float(__ushort_as_half((unsigned short)(pc & 0xFFFFu)));
    float w3 = __half2float(__ushort_as_half((unsigned short)(pd & 0xFFFFu)));
    const uint4* y0 = (const uint4*)(Yh + (size_t)s0 * 96 + q * 16);
    const uint4* y1 = (const uint4*)(Yh + (size_t)s1 * 96 + q * 16);
    const uint4* y2 = (const uint4*)(Yh + (size_t)s2 * 96 + q * 16);
    const uint4* y3 = (const uint4*)(Yh + (size_t)s3 * 96 + q * 16);
    uint4 a0 = y0[0], a1 = y0[1];
    uint4 b0 = y1[0], b1 = y1[1];
    uint4 c0 = y2[0], c1 = y2[1];
    uint4 d0 = y3[0], d1 = y3[1];
    ACC16(a0, a1, w0)
    ACC16(b0, b1, w1)
    ACC16(c0, c1, w2)
    ACC16(d0, d1, w3)
  }
  for (; p + 2 <= end; p += 2) {
    uint32_t pa = csr[p], pb = csr[p + 1];
    int s0 = pa >> 16, s1 = pb >> 16;
    if (s0 >= NNODES) s0 = 0;
    if (s1 >= NNODES) s1 = 0;
    float w0 = __half2float(__ushort_as_half((unsigned short)(pa & 0xFFFFu)));
    float w1 = __half2float(__ushort_as_half((unsigned short)(pb & 0xFFFFu)));
    const uint4* y0 = (const uint4*)(Yh + (size_t)s0 * 96 + q * 16);
    const uint4* y1 = (const uint4*)(Yh + (size_t)s1 * 96 + q * 16);
    uint4 a0 = y0[0], a1 = y0[1];
    uint4 b0 = y1[0], b1 = y1[1];
    ACC16(a0, a1, w0)
    ACC16(b0, b1, w1)
  }
  if (p < end) {
    uint32_t pa = csr[p];
    int s0 = pa >> 16;
    if (s0 >= NNODES) s0 = 0;
    float w0 = __half2float(__ushort_as_half((unsigned short)(pa & 0xFFFFu)));
    const uint4* y0 = (const uint4*)(Yh + (size_t)s0 * 96 + q * 16);
    uint4 a0 = y0[0], a1 = y0[1];
    ACC16(a0, a1, w0)
  }

  float iv = inv_in[n];
  float sc = 2.0f * inv_o[n];            // next-layer src scale, folded here
  const float* bp = bias + q * 16;
  float o[16];
#pragma unroll
  for (int i = 0; i < 16; ++i)
    o[i] = fmaxf(acc[i] * iv + bp[i], 0.f) * sc;
  uint32_t jb = (uint32_t)(n * 96 + q * 16);
#pragma unroll
  for (int i = 0; i < 16; ++i)
    o[i] = keep_bit(k0, k1, jb + i) ? o[i] : 0.f;
  float* xp = Xn + (size_t)n * 96 + q * 16;
  *(float4*)(xp + 0)  = make_float4(o[0], o[1], o[2], o[3]);
  *(float4*)(xp + 4)  = make_float4(o[4], o[5], o[6], o[7]);
  *(float4*)(xp + 8)  = make_float4(o[8], o[9], o[10], o[11]);
  *(float4*)(xp + 12) = make_float4(o[12], o[13], o[14], o[15]);
}

// ---------- layer 2: CSR gather (fp16 Y2) + bias + log_softmax, 2-edge unroll ----------
__global__ __launch_bounds__(256) void gather16_lsm_kernel(
    const __half* __restrict__ Y2h, const uint32_t* __restrict__ csr,
    const int* __restrict__ row_ptr, const float* __restrict__ inv_in,
    const float* __restrict__ b2, float* __restrict__ out) {
  int n = blockIdx.x * 256 + threadIdx.x;
  if (n >= NNODES) return;
  int beg = row_ptr[n], end = row_ptr[n + 1];
  float acc[16];
#pragma unroll
  for (int i = 0; i < 16; ++i) acc[i] = 0.f;

  int p = beg;
  for (; p + 2 <= end; p += 2) {
    uint32_t pa = csr[p], pb = csr[p + 1];
    int sa = pa >> 16, sb = pb >> 16;
    if (sa >= NNODES) sa = 0;
    if (sb >= NNODES) sb = 0;
    float wa = __half2float(__ushort_as_half((unsigned short)(pa & 0xFFFFu)));
    float wb = __half2float(__ushort_as_half((unsigned short)(pb & 0xFFFFu)));
    const uint4* ya = (const uint4*)(Y2h + (size_t)sa * 16);
    const uint4* yb = (const uint4*)(Y2h + (size_t)sb * 16);
    uint4 a0 = ya[0], a1 = ya[1];
    uint4 b0 = yb[0], b1 = yb[1];
    ACC16(a0, a1, wa)
    ACC16(b0, b1, wb)
  }
  if (p < end) {
    uint32_t pa = csr[p];
    int sa = pa >> 16;
    if (sa >= NNODES) sa = 0;
    float wa = __half2float(__ushort_as_half((unsigned short)(pa & 0xFFFFu)));
    const uint4* ya = (const uint4*)(Y2h + (size_t)sa * 16);
    uint4 a0 = ya[0], a1 = ya[1];
    ACC16(a0, a1, wa)
  }

  float iv = inv_in[n];
  float v[16];
#pragma unroll
  for (int i = 0; i < 16; ++i) v[i] = acc[i] * iv + b2[i];
  float m = v[0];
#pragma unroll
  for (int i = 1; i < 16; i++) m = fmaxf(m, v[i]);
  float s = 0.f;
#pragma unroll
  for (int i = 0; i < 16; i++) s += expf(v[i] - m);
  float ls = logf(s);
  float* orow = out + (size_t)n * 16;
#pragma unroll
  for (int i = 0; i < 16; i++) orow[i] = v[i] - m - ls;
}

extern "C" void kernel_launch(void* const* d_in, const int* in_sizes, int n_in,
                              void* d_out, int out_size, void* d_ws, size_t ws_size,
                              hipStream_t stream) {
  const float* feat = (const float*)d_in[0];
  const float* ew   = (const float*)d_in[1];
  const int*   src  = (const int*)d_in[2];
  const int*   dst  = (const int*)d_in[3];
  const float* W0   = (const float*)d_in[4];
  const float* b0   = (const float*)d_in[5];
  const float* W1   = (const float*)d_in[6];
  const float* b1   = (const float*)d_in[7];
  const float* W2   = (const float*)d_in[8];
  const float* b2   = (const float*)d_in[9];
  float* out = (float*)d_out;

  char* base = (char*)d_ws;
  size_t off = 0;
  auto take = [&](size_t nbytes) {
    void* q = base + off;
    off += (nbytes + 255) & ~(size_t)255;
    return q;
  };
  int*      ideg    = (int*)take((size_t)NNODES * 4);
  int*      row_ptr = (int*)take((size_t)(NNODES + 1) * 4);
  int*      bsum    = (int*)take((size_t)NB * 4);
  int*      boff    = (int*)take((size_t)NB * 4);
  float*    inv_o   = (float*)take((size_t)NNODES * 4);
  float*    inv_i   = (float*)take((size_t)NNODES * 4);
  uint32_t* slabD   = (uint32_t*)take((size_t)NC * NR * RWORDS * 4);  // 20 MB
  uint32_t* slabS   = (uint32_t*)take((size_t)NC * NR * RWORDS * 4);  // 20 MB
  uint32_t* rel32   = (uint32_t*)take((size_t)NC * NWORDS * 4);       // 20 MB
  uint32_t* csr     = (uint32_t*)take((size_t)NEDGES * 4);
  float*    X       = (float*)take((size_t)NNODES * NHID * 4);
  __half*   Yh      = (__half*)take((size_t)NNODES * NHID * 2);
  __half*   Y2h     = (__half*)take((size_t)NNODES * NCLS * 2);
  (void)ws_size; (void)in_sizes; (void)n_in; (void)out_size;

  uint32_t k[3][2];
  for (uint32_t i = 0; i < 3; i++) tf2x32(0u, 42u, 0u, i, k[i][0], k[i][1]);

  const int GW = (NWORDS + 255) / 256;   // 98 blocks for word-indexed kernels

  // graph build: atomic-free, grid = NC*NR = 800 (~3 blocks/CU)
  hist_kernel<<<NC * NR, 256, 0, stream>>>(src, dst, slabD, slabS);
  reduce_base_kernel<<<GW, 256, 0, stream>>>(slabD, slabS, ideg, inv_o, inv_i, rel32);
  scan_blocks_kernel<<<NB, 256, 0, stream>>>(ideg, bsum);
  scan_top_kernel<<<1, 256, 0, stream>>>(bsum, boff);
  scan_write_kernel<<<NB, 256, 0, stream>>>(ideg, boff, row_ptr);
  fillh_kernel<<<NC * NR, 256, 0, stream>>>(src, dst, ew, rel32, row_ptr, csr);

  const int NELEM = NNODES * NHID;
  const int G96  = (NNODES + 127) / 128;   // 391 blocks (128 rows/block)
  const int G16  = (NNODES + 511) / 512;
  const int GGD  = (NNODES * 6 + 255) / 256;

  // layer 0: feat --mask0*2inv_o--> X --gemm--> Yh --gather+mask1*2inv_o--> X
  drop0_kernel<<<(NELEM + 255) / 256, 256, 0, stream>>>(feat, inv_o, X, k[0][0], k[0][1]);
  gemm96_kernel<<<G96, 256, 0, stream>>>(X, W0, Yh);
  gather96_drop_kernel<<<GGD, 256, 0, stream>>>(Yh, csr, row_ptr, inv_i, inv_o, b0, X, k[1][0], k[1][1]);
  // layer 1: X --gemm--> Yh --gather+mask2*2inv_o--> X
  gemm96_kernel<<<G96, 256, 0, stream>>>(X, W1, Yh);
  gather96_drop_kernel<<<GGD, 256, 0, stream>>>(Yh, csr, row_ptr, inv_i, inv_o, b1, X, k[2][0], k[2][1]);
  // layer 2: X --gemm16--> Y2h --gather+lsm--> out
  gemm16_kernel<<<G16, 256, 0, stream>>>(X, W2, Y2h);
  gather16_lsm_kernel<<<(NNODES + 255) / 256, 256, 0, stream>>>(Y2h, csr, row_ptr, inv_i, b2, out);
}

// Round 15
// 303.316 us; speedup vs baseline: 1.0984x; 1.0250x over previous
//
#include <hip/hip_runtime.h>
#include <hip/hip_fp16.h>
#include <stdint.h>

#define NNODES 50000
#define NEDGES 800000
#define NHID 96
#define NCLS 16
#define NB ((NNODES + 255) / 256)   // 196 scan blocks

// graph build: NC edge-chunks x NR node-ranges; per-block LDS histogram of one
// range (12500 nodes, u16 pair-packed into 6250 u32 words). grid = NC*NR = 800.
#define NC 200
#define NR 4
#define EPB (NEDGES / NC)           // 4000 edges per chunk
#define RNODES (NNODES / NR)        // 12500 nodes per range
#define RWORDS (RNODES / 2)         // 6250 packed words
#define NWORDS (NNODES / 2)         // 25000 global packed words
#define NDROP ((NNODES * NHID + 255) / 256)   // 18750 drop0 blocks

// ---------- JAX Threefry-2x32 (Random123 20-round, matches jax._src.prng) ----------
__host__ __device__ inline void tf2x32(uint32_t k0, uint32_t k1, uint32_t x0, uint32_t x1,
                                       uint32_t& o0, uint32_t& o1) {
  uint32_t k2 = k0 ^ k1 ^ 0x1BD11BDAu;
#define TFROT(v, r) (((v) << (r)) | ((v) >> (32 - (r))))
#define TFR(r) { x0 += x1; x1 = TFROT(x1, r); x1 ^= x0; }
  x0 += k0; x1 += k1;
  TFR(13) TFR(15) TFR(26) TFR(6)
  x0 += k1; x1 += k2 + 1u;
  TFR(17) TFR(29) TFR(16) TFR(24)
  x0 += k2; x1 += k0 + 2u;
  TFR(13) TFR(15) TFR(26) TFR(6)
  x0 += k0; x1 += k1 + 3u;
  TFR(17) TFR(29) TFR(16) TFR(24)
  x0 += k1; x1 += k2 + 4u;
  TFR(13) TFR(15) TFR(26) TFR(6)
  x0 += k2; x1 += k0 + 5u;
  o0 = x0; o1 = x1;
#undef TFR
#undef TFROT
}

__device__ inline bool keep_bit(uint32_t k0, uint32_t k1, uint32_t j) {
  uint32_t o0, o1;
  tf2x32(k0, k1, 0u, j, o0, o1);
  return (((o0 ^ o1) >> 31) == 0u);   // uniform<0.5 <=> MSB==0
}

// ---------- pass 1: per-(chunk,range) LDS histograms of dst and src ----------
__global__ __launch_bounds__(256) void hist_kernel(
    const int* __restrict__ src, const int* __restrict__ dst,
    uint32_t* __restrict__ slabD, uint32_t* __restrict__ slabS) {
  __shared__ uint32_t HD[RWORDS];
  __shared__ uint32_t HS[RWORDS];
  const int tid = threadIdx.x, b = blockIdx.x;
  const int c = b / NR, r = b - c * NR;
  const int e0 = c * EPB, e1 = e0 + EPB;
  const int nbase = r * RNODES;
  for (int w = tid; w < RWORDS; w += 256) { HD[w] = 0; HS[w] = 0; }
  __syncthreads();
  int e = e0 + tid;
  for (; e + 768 < e1; e += 1024) {
    int d0 = dst[e] - nbase,       d1 = dst[e + 256] - nbase;
    int d2 = dst[e + 512] - nbase, d3 = dst[e + 768] - nbase;
    int s0 = src[e] - nbase,       s1 = src[e + 256] - nbase;
    int s2 = src[e + 512] - nbase, s3 = src[e + 768] - nbase;
    if ((unsigned)d0 < (unsigned)RNODES) atomicAdd(&HD[d0 >> 1], 1u << ((d0 & 1) * 16));
    if ((unsigned)d1 < (unsigned)RNODES) atomicAdd(&HD[d1 >> 1], 1u << ((d1 & 1) * 16));
    if ((unsigned)d2 < (unsigned)RNODES) atomicAdd(&HD[d2 >> 1], 1u << ((d2 & 1) * 16));
    if ((unsigned)d3 < (unsigned)RNODES) atomicAdd(&HD[d3 >> 1], 1u << ((d3 & 1) * 16));
    if ((unsigned)s0 < (unsigned)RNODES) atomicAdd(&HS[s0 >> 1], 1u << ((s0 & 1) * 16));
    if ((unsigned)s1 < (unsigned)RNODES) atomicAdd(&HS[s1 >> 1], 1u << ((s1 & 1) * 16));
    if ((unsigned)s2 < (unsigned)RNODES) atomicAdd(&HS[s2 >> 1], 1u << ((s2 & 1) * 16));
    if ((unsigned)s3 < (unsigned)RNODES) atomicAdd(&HS[s3 >> 1], 1u << ((s3 & 1) * 16));
  }
  for (; e < e1; e += 256) {
    int d = dst[e] - nbase;
    if ((unsigned)d < (unsigned)RNODES) atomicAdd(&HD[d >> 1], 1u << ((d & 1) * 16));
    int s = src[e] - nbase;
    if ((unsigned)s < (unsigned)RNODES) atomicAdd(&HS[s >> 1], 1u << ((s & 1) * 16));
  }
  __syncthreads();
  uint32_t* dpD = slabD + (size_t)b * RWORDS;
  uint32_t* dpS = slabS + (size_t)b * RWORDS;
  for (int w = tid; w < RWORDS; w += 256) { dpD[w] = HD[w]; dpS[w] = HS[w]; }
}

// ---------- merged reduce + relative-base + inv: one stream over the slabs ----------
__global__ __launch_bounds__(256) void reduce_base_kernel(
    const uint32_t* __restrict__ slabD, const uint32_t* __restrict__ slabS,
    int* __restrict__ ideg, float* __restrict__ inv_o, float* __restrict__ inv_i,
    uint32_t* __restrict__ rel32) {
  int gw = blockIdx.x * 256 + threadIdx.x;
  if (gw >= NWORDS) return;
  int r = gw / RWORDS, lw = gw - r * RWORDS;
  int n0 = r * RNODES + 2 * lw;
  uint32_t runL = 0, runH = 0, lo = 0, ho = 0;
#pragma unroll 4
  for (int c = 0; c < NC; ++c) {
    rel32[(size_t)c * NWORDS + gw] = (runL & 0xFFFFu) | (runH << 16);
    uint32_t vi = slabD[(size_t)(c * NR + r) * RWORDS + lw];
    uint32_t vo = slabS[(size_t)(c * NR + r) * RWORDS + lw];
    runL += vi & 0xFFFFu; runH += vi >> 16;
    lo   += vo & 0xFFFFu; ho   += vo >> 16;
  }
  ideg[n0] = (int)runL; ideg[n0 + 1] = (int)runH;
  inv_i[n0]     = rsqrtf(fmaxf((float)runL, 1.0f));
  inv_i[n0 + 1] = rsqrtf(fmaxf((float)runH, 1.0f));
  inv_o[n0]     = rsqrtf(fmaxf((float)lo, 1.0f));
  inv_o[n0 + 1] = rsqrtf(fmaxf((float)ho, 1.0f));
}

// ---------- hierarchical exclusive scan of ideg -> row_ptr ----------
__global__ __launch_bounds__(256) void scan_blocks_kernel(
    const int* __restrict__ ideg, int* __restrict__ bsum) {
  __shared__ int lds[256];
  const int tid = threadIdx.x;
  int i = blockIdx.x * 256 + tid;
  lds[tid] = (i < NNODES) ? ideg[i] : 0;
  __syncthreads();
  for (int off = 128; off > 0; off >>= 1) {
    if (tid < off) lds[tid] += lds[tid + off];
    __syncthreads();
  }
  if (tid == 0) bsum[blockIdx.x] = lds[0];
}

__global__ __launch_bounds__(256) void scan_top_kernel(
    const int* __restrict__ bsum, int* __restrict__ boff) {
  __shared__ int lds[256];
  const int tid = threadIdx.x;
  int v = (tid < NB) ? bsum[tid] : 0;
  lds[tid] = v;
  __syncthreads();
  for (int off = 1; off < 256; off <<= 1) {
    int t = (tid >= off) ? lds[tid - off] : 0;
    __syncthreads();
    lds[tid] += t;
    __syncthreads();
  }
  if (tid < NB) boff[tid] = lds[tid] - v;   // exclusive
}

__global__ __launch_bounds__(256) void scan_write_kernel(
    const int* __restrict__ ideg, const int* __restrict__ boff,
    int* __restrict__ row_ptr) {
  __shared__ int lds[256];
  const int tid = threadIdx.x;
  int i = blockIdx.x * 256 + tid;
  int v = (i < NNODES) ? ideg[i] : 0;
  lds[tid] = v;
  __syncthreads();
  for (int off = 1; off < 256; off <<= 1) {
    int t = (tid >= off) ? lds[tid - off] : 0;
    __syncthreads();
    lds[tid] += t;
    __syncthreads();
  }
  if (i < NNODES) row_ptr[i] = boff[blockIdx.x] + lds[tid] - v;
  if (i == 0) row_ptr[NNODES] = NEDGES;
}

// ---------- fused pass 2: CSR fill (blocks 0..NC*NR) + layer-0 dropout (rest) ----------
// fillh: pos = row_ptr[d] + rel16[c][d] + local rank; non-temporal scattered stores.
// drop0: X[j] = keep ? h[j]*2*inv_o[n] : 0.  Independent work co-scheduled to hide
// fillh's latency-bound tail under drop0's streaming waves.
__global__ __launch_bounds__(256) void fill_drop_kernel(
    const int* __restrict__ src, const int* __restrict__ dst, const float* __restrict__ ew,
    const uint32_t* __restrict__ rel32, const int* __restrict__ row_ptr,
    uint32_t* __restrict__ csr,
    const float* __restrict__ h, const float* __restrict__ inv_o,
    float* __restrict__ X, uint32_t k0, uint32_t k1) {
  __shared__ uint32_t H[RWORDS];
  const int tid = threadIdx.x, b = blockIdx.x;
  if (b >= NC * NR) {
    // ---- drop0 branch ----
    int j = (b - NC * NR) * 256 + tid;
    if (j < NNODES * NHID) {
      int n = j / NHID;
      X[j] = keep_bit(k0, k1, (uint32_t)j) ? h[j] * (2.0f * inv_o[n]) : 0.0f;
    }
    return;
  }
  // ---- fillh branch ----
  const int c = b / NR, r = b - c * NR;
  const int e0 = c * EPB, e1 = e0 + EPB;
  const int nbase = r * RNODES;
  const uint32_t* rel = rel32 + (size_t)c * NWORDS;
  for (int w = tid; w < RWORDS; w += 256) H[w] = 0;
  __syncthreads();
  int e = e0 + tid;
  for (; e + 256 < e1; e += 512) {
    int da = dst[e], db = dst[e + 256];
    int sa = src[e], sb = src[e + 256];
    float wa = ew[e], wb = ew[e + 256];
    int la = da - nbase, lb = db - nbase;
    bool ia = (unsigned)la < (unsigned)RNODES;
    bool ib = (unsigned)lb < (unsigned)RNODES;
    if (ia) {
      int sh = (la & 1) * 16;
      uint32_t old = atomicAdd(&H[la >> 1], 1u << sh);
      int rank = (int)((old >> sh) & 0xFFFFu);
      int rel16 = (int)((rel[da >> 1] >> sh) & 0xFFFFu);
      int pos = row_ptr[da] + rel16 + rank;
      if ((unsigned)pos < (unsigned)NEDGES) {
        uint32_t v = ((uint32_t)sa << 16) | (uint32_t)__half_as_ushort(__float2half_rn(wa));
        __builtin_nontemporal_store(v, &csr[pos]);
      }
    }
    if (ib) {
      int sh = (lb & 1) * 16;
      uint32_t old = atomicAdd(&H[lb >> 1], 1u << sh);
      int rank = (int)((old >> sh) & 0xFFFFu);
      int rel16 = (int)((rel[db >> 1] >> sh) & 0xFFFFu);
      int pos = row_ptr[db] + rel16 + rank;
      if ((unsigned)pos < (unsigned)NEDGES) {
        uint32_t v = ((uint32_t)sb << 16) | (uint32_t)__half_as_ushort(__float2half_rn(wb));
        __builtin_nontemporal_store(v, &csr[pos]);
      }
    }
  }
  for (; e < e1; e += 256) {
    int d = dst[e];
    int ld = d - nbase;
    if ((unsigned)ld < (unsigned)RNODES) {
      int sh = (ld & 1) * 16;
      uint32_t old = atomicAdd(&H[ld >> 1], 1u << sh);
      int rank = (int)((old >> sh) & 0xFFFFu);
      int rel16 = (int)((rel[d >> 1] >> sh) & 0xFFFFu);
      int pos = row_ptr[d] + rel16 + rank;
      if ((unsigned)pos < (unsigned)NEDGES) {
        uint32_t v = ((uint32_t)src[e] << 16) | (uint32_t)__half_as_ushort(__float2half_rn(ew[e]));
        __builtin_nontemporal_store(v, &csr[pos]);
      }
    }
  }
}

// ---------- GEMM96: Yh[N,96](fp16) = X[N,96](fp32) @ W[96,96], LDS-staged W ----------
// thread tile = 4 rows x 12 cols (proven shape; 8x12 regressed via VGPR pressure).
__global__ __launch_bounds__(256) void gemm96_kernel(
    const float* __restrict__ X, const float* __restrict__ W, __half* __restrict__ Yh) {
  __shared__ float Wl[96 * 96];
  const int tid = threadIdx.x;
  {
    const float4* Wg = (const float4*)W;
    float4* Ws = (float4*)Wl;
#pragma unroll
    for (int i = 0; i < 9; ++i)
      Ws[tid + i * 256] = Wg[tid + i * 256];
  }
  __syncthreads();

  const int cg = tid & 7;
  const int rq = tid >> 3;
  const int row0 = blockIdx.x * 128 + rq * 4;
  const int c0 = cg * 12;

  float acc[4][12];
#pragma unroll
  for (int r = 0; r < 4; ++r)
#pragma unroll
    for (int c = 0; c < 12; ++c) acc[r][c] = 0.f;

  const float* xr[4];
#pragma unroll
  for (int r = 0; r < 4; ++r) {
    int rr = row0 + r; if (rr > NNODES - 1) rr = NNODES - 1;
    xr[r] = X + (size_t)rr * 96;
  }

  for (int k = 0; k < 96; k += 4) {
    float4 x4[4];
#pragma unroll
    for (int r = 0; r < 4; ++r) x4[r] = *(const float4*)(xr[r] + k);
#pragma unroll
    for (int kk = 0; kk < 4; ++kk) {
      const float4* wp = (const float4*)(Wl + (k + kk) * 96 + c0);
      float4 w0 = wp[0], w1 = wp[1], w2 = wp[2];
      float xv[4] = { (&x4[0].x)[kk], (&x4[1].x)[kk], (&x4[2].x)[kk], (&x4[3].x)[kk] };
#pragma unroll
      for (int r = 0; r < 4; ++r) {
        acc[r][0]  += xv[r] * w0.x; acc[r][1]  += xv[r] * w0.y;
        acc[r][2]  += xv[r] * w0.z; acc[r][3]  += xv[r] * w0.w;
        acc[r][4]  += xv[r] * w1.x; acc[r][5]  += xv[r] * w1.y;
        acc[r][6]  += xv[r] * w1.z; acc[r][7]  += xv[r] * w1.w;
        acc[r][8]  += xv[r] * w2.x; acc[r][9]  += xv[r] * w2.y;
        acc[r][10] += xv[r] * w2.z; acc[r][11] += xv[r] * w2.w;
      }
    }
  }

#pragma unroll
  for (int r = 0; r < 4; ++r) {
    int rr = row0 + r;
    if (rr < NNODES) {
      __half2* hp = (__half2*)(Yh + (size_t)rr * 96 + c0);
#pragma unroll
      for (int c = 0; c < 6; ++c)
        hp[c] = __floats2half2_rn(acc[r][2 * c], acc[r][2 * c + 1]);
    }
  }
}

// ---------- GEMM16: Y2h[N,16](fp16) = X[N,96] @ W[96,16], LDS-staged W ----------
__global__ __launch_bounds__(256) void gemm16_kernel(
    const float* __restrict__ X, const float* __restrict__ W, __half* __restrict__ Y2h) {
  __shared__ float Wl[96 * 16];
  const int tid = threadIdx.x;
  {
    const float4* Wg = (const float4*)W;
    float4* Ws = (float4*)Wl;
    for (int i = tid; i < 384; i += 256) Ws[i] = Wg[i];
  }
  __syncthreads();

  const int row0 = blockIdx.x * 512 + tid * 2;
  const float* xr[2];
#pragma unroll
  for (int r = 0; r < 2; ++r) {
    int rr = row0 + r; if (rr > NNODES - 1) rr = NNODES - 1;
    xr[r] = X + (size_t)rr * 96;
  }

  float acc[2][16];
#pragma unroll
  for (int r = 0; r < 2; ++r)
#pragma unroll
    for (int c = 0; c < 16; ++c) acc[r][c] = 0.f;

  for (int k = 0; k < 96; k += 4) {
    float4 x4[2];
#pragma unroll
    for (int r = 0; r < 2; ++r) x4[r] = *(const float4*)(xr[r] + k);
#pragma unroll
    for (int kk = 0; kk < 4; ++kk) {
      const float4* wp = (const float4*)(Wl + (k + kk) * 16);
      float4 w0 = wp[0], w1 = wp[1], w2 = wp[2], w3 = wp[3];
#pragma unroll
      for (int r = 0; r < 2; ++r) {
        float xv = (&x4[r].x)[kk];
        acc[r][0]  += xv * w0.x; acc[r][1]  += xv * w0.y;
        acc[r][2]  += xv * w0.z; acc[r][3]  += xv * w0.w;
        acc[r][4]  += xv * w1.x; acc[r][5]  += xv * w1.y;
        acc[r][6]  += xv * w1.z; acc[r][7]  += xv * w1.w;
        acc[r][8]  += xv * w2.x; acc[r][9]  += xv * w2.y;
        acc[r][10] += xv * w2.z; acc[r][11] += xv * w2.w;
        acc[r][12] += xv * w3.x; acc[r][13] += xv * w3.y;
        acc[r][14] += xv * w3.z; acc[r][15] += xv * w3.w;
      }
    }
  }

#pragma unroll
  for (int r = 0; r < 2; ++r) {
    int rr = row0 + r;
    if (rr < NNODES) {
      __half2* hp = (__half2*)(Y2h + (size_t)rr * 16);
#pragma unroll
      for (int c = 0; c < 8; ++c)
        hp[c] = __floats2half2_rn(acc[r][2 * c], acc[r][2 * c + 1]);
    }
  }
}

// ---------- CSR gather (fp16 Y) + inv_in*bias + ReLU + dropout + 2*inv_o ----------
#define ACC16(u0, u1, wt) { \
  float2 g0 = __half22float2(*(__half2*)&u0.x); \
  float2 g1 = __half22float2(*(__half2*)&u0.y); \
  float2 g2 = __half22float2(*(__half2*)&u0.z); \
  float2 g3 = __half22float2(*(__half2*)&u0.w); \
  float2 g4 = __half22float2(*(__half2*)&u1.x); \
  float2 g5 = __half22float2(*(__half2*)&u1.y); \
  float2 g6 = __half22float2(*(__half2*)&u1.z); \
  float2 g7 = __half22float2(*(__half2*)&u1.w); \
  acc[0]  += g0.x * wt; acc[1]  += g0.y * wt; \
  acc[2]  += g1.x * wt; acc[3]  += g1.y * wt; \
  acc[4]  += g2.x * wt; acc[5]  += g2.y * wt; \
  acc[6]  += g3.x * wt; acc[7]  += g3.y * wt; \
  acc[8]  += g4.x * wt; acc[9]  += g4.y * wt; \
  acc[10] += g5.x * wt; acc[11] += g5.y * wt; \
  acc[12] += g6.x * wt; acc[13] += g6.y * wt; \
  acc[14] += g7.x * wt; acc[15] += g7.y * wt; }

__global__ __launch_bounds__(256) void gather96_drop_kernel(
    const __half* __restrict__ Yh, const uint32_t* __restrict__ csr,
    const int* __restrict__ row_ptr, const float* __restrict__ inv_in,
    const float* __restrict__ inv_o, const float* __restrict__ bias,
    float* __restrict__ Xn, uint32_t k0, uint32_t k1) {
  int tid = blockIdx.x * 256 + threadIdx.x;
  int n = tid / 6;
  int q = tid - n * 6;        // 16-dim chunk within the 96-dim row
  if (n >= NNODES) return;
  int beg = row_ptr[n], end = row_ptr[n + 1];
  float acc[16];
#pragma unroll
  for (int i = 0; i < 16; ++i) acc[i] = 0.f;

  int p = beg;
  for (; p + 4 <= end; p += 4) {
    uint32_t pa = csr[p], pb = csr[p + 1], pc = csr[p + 2], pd = csr[p + 3];
    int s0 = pa >> 16, s1 = pb >> 16, s2 = pc >> 16, s3 = pd >> 16;
    if (s0 >= NNODES) s0 = 0;
    if (s1 >= NNODES) s1 = 0;
    if (s2 >= NNODES) s2 = 0;
    if (s3 >= NNODES) s3 = 0;
    float w0 = __half2float(__ushort_as_half((unsigned short)(pa & 0xFFFFu)));
    float w1 = __half2float(__ushort_as_half((unsigned short)(pb & 0xFFFFu)));
    float w2 = __half2float(__ushort_as_half((unsigned short)(pc & 0xFFFFu)));
    float w3 = __half2float(__ushort_as_half((unsigned short)(pd & 0xFFFFu)));
    const uint4* y0 = (const uint4*)(Yh + (size_t)s0 * 96 + q * 16);
    const uint4* y1 = (const uint4*)(Yh + (size_t)s1 * 96 + q * 16);
    const uint4* y2 = (const uint4*)(Yh + (size_t)s2 * 96 + q * 16);
    const uint4* y3 = (const uint4*)(Yh + (size_t)s3 * 96 + q * 16);
    uint4 a0 = y0[0], a1 = y0[1];
    uint4 b0 = y1[0], b1 = y1[1];
    uint4 c0 = y2[0], c1 = y2[1];
    uint4 d0 = y3[0], d1 = y3[1];
    ACC16(a0, a1, w0)
    ACC16(b0, b1, w1)
    ACC16(c0, c1, w2)
    ACC16(d0, d1, w3)
  }
  for (; p + 2 <= end; p += 2) {
    uint32_t pa = csr[p], pb = csr[p + 1];
    int s0 = pa >> 16, s1 = pb >> 16;
    if (s0 >= NNODES) s0 = 0;
    if (s1 >= NNODES) s1 = 0;
    float w0 = __half2float(__ushort_as_half((unsigned short)(pa & 0xFFFFu)));
    float w1 = __half2float(__ushort_as_half((unsigned short)(pb & 0xFFFFu)));
    const uint4* y0 = (const uint4*)(Yh + (size_t)s0 * 96 + q * 16);
    const uint4* y1 = (const uint4*)(Yh + (size_t)s1 * 96 + q * 16);
    uint4 a0 = y0[0], a1 = y0[1];
    uint4 b0 = y1[0], b1 = y1[1];
    ACC16(a0, a1, w0)
    ACC16(b0, b1, w1)
  }
  if (p < end) {
    uint32_t pa = csr[p];
    int s0 = pa >> 16;
    if (s0 >= NNODES) s0 = 0;
    float w0 = __half2float(__ushort_as_half((unsigned short)(pa & 0xFFFFu)));
    const uint4* y0 = (const uint4*)(Yh + (size_t)s0 * 96 + q * 16);
    uint4 a0 = y0[0], a1 = y0[1];
    ACC16(a0, a1, w0)
  }

  float iv = inv_in[n];
  float sc = 2.0f * inv_o[n];            // next-layer src scale, folded here
  const float* bp = bias + q * 16;
  float o[16];
#pragma unroll
  for (int i = 0; i < 16; ++i)
    o[i] = fmaxf(acc[i] * iv + bp[i], 0.f) * sc;
  uint32_t jb = (uint32_t)(n * 96 + q * 16);
#pragma unroll
  for (int i = 0; i < 16; ++i)
    o[i] = keep_bit(k0, k1, jb + i) ? o[i] : 0.f;
  float* xp = Xn + (size_t)n * 96 + q * 16;
  *(float4*)(xp + 0)  = make_float4(o[0], o[1], o[2], o[3]);
  *(float4*)(xp + 4)  = make_float4(o[4], o[5], o[6], o[7]);
  *(float4*)(xp + 8)  = make_float4(o[8], o[9], o[10], o[11]);
  *(float4*)(xp + 12) = make_float4(o[12], o[13], o[14], o[15]);
}

// ---------- layer 2: CSR gather (fp16 Y2) + bias + log_softmax, 2-edge unroll ----------
__global__ __launch_bounds__(256) void gather16_lsm_kernel(
    const __half* __restrict__ Y2h, const uint32_t* __restrict__ csr,
    const int* __restrict__ row_ptr, const float* __restrict__ inv_in,
    const float* __restrict__ b2, float* __restrict__ out) {
  int n = blockIdx.x * 256 + threadIdx.x;
  if (n >= NNODES) return;
  int beg = row_ptr[n], end = row_ptr[n + 1];
  float acc[16];
#pragma unroll
  for (int i = 0; i < 16; ++i) acc[i] = 0.f;

  int p = beg;
  for (; p + 2 <= end; p += 2) {
    uint32_t pa = csr[p], pb = csr[p + 1];
    int sa = pa >> 16, sb = pb >> 16;
    if (sa >= NNODES) sa = 0;
    if (sb >= NNODES) sb = 0;
    float wa = __half2float(__ushort_as_half((unsigned short)(pa & 0xFFFFu)));
    float wb = __half2float(__ushort_as_half((unsigned short)(pb & 0xFFFFu)));
    const uint4* ya = (const uint4*)(Y2h + (size_t)sa * 16);
    const uint4* yb = (const uint4*)(Y2h + (size_t)sb * 16);
    uint4 a0 = ya[0], a1 = ya[1];
    uint4 b0 = yb[0], b1 = yb[1];
    ACC16(a0, a1, wa)
    ACC16(b0, b1, wb)
  }
  if (p < end) {
    uint32_t pa = csr[p];
    int sa = pa >> 16;
    if (sa >= NNODES) sa = 0;
    float wa = __half2float(__ushort_as_half((unsigned short)(pa & 0xFFFFu)));
    const uint4* ya = (const uint4*)(Y2h + (size_t)sa * 16);
    uint4 a0 = ya[0], a1 = ya[1];
    ACC16(a0, a1, wa)
  }

  float iv = inv_in[n];
  float v[16];
#pragma unroll
  for (int i = 0; i < 16; ++i) v[i] = acc[i] * iv + b2[i];
  float m = v[0];
#pragma unroll
  for (int i = 1; i < 16; i++) m = fmaxf(m, v[i]);
  float s = 0.f;
#pragma unroll
  for (int i = 0; i < 16; i++) s += expf(v[i] - m);
  float ls = logf(s);
  float* orow = out + (size_t)n * 16;
#pragma unroll
  for (int i = 0; i < 16; i++) orow[i] = v[i] - m - ls;
}

extern "C" void kernel_launch(void* const* d_in, const int* in_sizes, int n_in,
                              void* d_out, int out_size, void* d_ws, size_t ws_size,
                              hipStream_t stream) {
  const float* feat = (const float*)d_in[0];
  const float* ew   = (const float*)d_in[1];
  const int*   src  = (const int*)d_in[2];
  const int*   dst  = (const int*)d_in[3];
  const float* W0   = (const float*)d_in[4];
  const float* b0   = (const float*)d_in[5];
  const float* W1   = (const float*)d_in[6];
  const float* b1   = (const float*)d_in[7];
  const float* W2   = (const float*)d_in[8];
  const float* b2   = (const float*)d_in[9];
  float* out = (float*)d_out;

  char* base = (char*)d_ws;
  size_t off = 0;
  auto take = [&](size_t nbytes) {
    void* q = base + off;
    off += (nbytes + 255) & ~(size_t)255;
    return q;
  };
  int*      ideg    = (int*)take((size_t)NNODES * 4);
  int*      row_ptr = (int*)take((size_t)(NNODES + 1) * 4);
  int*      bsum    = (int*)take((size_t)NB * 4);
  int*      boff    = (int*)take((size_t)NB * 4);
  float*    inv_o   = (float*)take((size_t)NNODES * 4);
  float*    inv_i   = (float*)take((size_t)NNODES * 4);
  uint32_t* slabD   = (uint32_t*)take((size_t)NC * NR * RWORDS * 4);  // 20 MB
  uint32_t* slabS   = (uint32_t*)take((size_t)NC * NR * RWORDS * 4);  // 20 MB
  uint32_t* rel32   = (uint32_t*)take((size_t)NC * NWORDS * 4);       // 20 MB
  uint32_t* csr     = (uint32_t*)take((size_t)NEDGES * 4);
  float*    X       = (float*)take((size_t)NNODES * NHID * 4);
  __half*   Yh      = (__half*)take((size_t)NNODES * NHID * 2);
  __half*   Y2h     = (__half*)take((size_t)NNODES * NCLS * 2);
  (void)ws_size; (void)in_sizes; (void)n_in; (void)out_size;

  uint32_t k[3][2];
  for (uint32_t i = 0; i < 3; i++) tf2x32(0u, 42u, 0u, i, k[i][0], k[i][1]);

  const int GW = (NWORDS + 255) / 256;   // 98 blocks for word-indexed kernels

  // graph build: atomic-free, grid = NC*NR = 800 (~3 blocks/CU)
  hist_kernel<<<NC * NR, 256, 0, stream>>>(src, dst, slabD, slabS);
  reduce_base_kernel<<<GW, 256, 0, stream>>>(slabD, slabS, ideg, inv_o, inv_i, rel32);
  scan_blocks_kernel<<<NB, 256, 0, stream>>>(ideg, bsum);
  scan_top_kernel<<<1, 256, 0, stream>>>(bsum, boff);
  scan_write_kernel<<<NB, 256, 0, stream>>>(ideg, boff, row_ptr);
  // fused: CSR fill (800 blocks) + layer-0 dropout (18750 blocks) co-scheduled
  fill_drop_kernel<<<NC * NR + NDROP, 256, 0, stream>>>(
      src, dst, ew, rel32, row_ptr, csr, feat, inv_o, X, k[0][0], k[0][1]);

  const int G96  = (NNODES + 127) / 128;   // 391 blocks (128 rows/block)
  const int G16  = (NNODES + 511) / 512;
  const int GGD  = (NNODES * 6 + 255) / 256;

  // layer 0: X --gemm--> Yh --gather+mask1*2inv_o--> X
  gemm96_kernel<<<G96, 256, 0, stream>>>(X, W0, Yh);
  gather96_drop_kernel<<<GGD, 256, 0, stream>>>(Yh, csr, row_ptr, inv_i, inv_o, b0, X, k[1][0], k[1][1]);
  // layer 1: X --gemm--> Yh --gather+mask2*2inv_o--> X
  gemm96_kernel<<<G96, 256, 0, stream>>>(X, W1, Yh);
  gather96_drop_kernel<<<GGD, 256, 0, stream>>>(Yh, csr, row_ptr, inv_i, inv_o, b1, X, k[2][0], k[2][1]);
  // layer 2: X --gemm16--> Y2h --gather+lsm--> out
  gemm16_kernel<<<G16, 256, 0, stream>>>(X, W2, Y2h);
  gather16_lsm_kernel<<<(NNODES + 255) / 256, 256, 0, stream>>>(Y2h, csr, row_ptr, inv_i, b2, out);
}